// Round 4
// baseline (90.679 us; speedup 1.0000x reference)
//
#include <hip/hip_runtime.h>

// Encoder_29661044146233 — round 4:
//  * channel q-order [66 node | 22 edge] (weights+bias permuted in prep) ->
//    conv1 staging is a contiguous row copy: 23 unrolled float2 loads/thread
//  * 2 threads per frame staging for all convs (wide, independent, clustered loads)
//  * graph blocks fused in conv epilogue (unchanged from r3, q-order indices)

static constexpr int Jn   = 22;
static constexpr int C4   = 88;     // 88 channels, q-order: q<66 node(j=q/3,c=q%3), q>=66 edge(j=q-66)
static constexpr int KK   = 352;    // 4 taps * 88  (k = tap*88 + q)
static constexpr int NPAD = 96;     // padded out-channels (6 tiles of 16)
static constexpr int LROW = 104;    // LDS X row stride in ushorts (208 B, 16B-aligned rows)
static constexpr int YROW = 101;    // Ytile row stride in floats
static constexpr int NFR  = 130;    // input frames per block (2*64 + 2 halo)

typedef __attribute__((ext_vector_type(8))) short    short8;
typedef __attribute__((ext_vector_type(4))) float    floatx4;
typedef __attribute__((ext_vector_type(4))) unsigned uintx4;

__device__ constexpr int TOPc[Jn] = {0,0,1,2,3,4,0,6,7,8,0,10,11,12,12,14,15,16,12,18,19,20};

__device__ __forceinline__ unsigned short f2bf(float f) {
    unsigned u = __builtin_bit_cast(unsigned, f);
    unsigned r = (u + 0x7FFFu + ((u >> 16) & 1u)) >> 16;
    return (unsigned short)r;
}
__device__ __forceinline__ int qmap(int q) {          // q-order -> reference 4j+c channel
    return (q < 66) ? 4 * (q / 3) + (q % 3) : 4 * (q - 66) + 3;
}

struct GW {
    const float *n2n_w, *n2n_b, *e2n_we, *e2n_wn, *e2n_b;
    const float *n2e_wn, *n2e_we, *n2e_b, *lin_w, *lin_b;
};

// ---- prep: weights fp32 (88,88,4)[co_src][ci_src][tap] -> bf16 [96][352] q-order both sides;
//      biases permuted to q-order f32 [3][96] ----
__global__ __launch_bounds__(256)
void prep_weights(const float* __restrict__ w1, const float* __restrict__ w2,
                  const float* __restrict__ w3,
                  const float* __restrict__ b1, const float* __restrict__ b2,
                  const float* __restrict__ b3,
                  unsigned short* __restrict__ wo, float* __restrict__ bo)
{
    const int i = blockIdx.x * 256 + threadIdx.x;
    constexpr int per = NPAD * KK;
    if (i < 3 * per) {
        const int s = i / per, r = i - s * per;
        const int co = r / KK, k = r - co * KK;
        const int tap = k / C4, q = k - tap * C4;
        const float* w = (s == 0) ? w1 : (s == 1) ? w2 : w3;
        float v = 0.f;
        if (co < C4) v = w[((size_t)qmap(co) * C4 + qmap(q)) * 4 + tap];
        wo[i] = f2bf(v);
    } else if (i < 3 * per + 3 * NPAD) {
        const int j = i - 3 * per;
        const int s = j / NPAD, q = j - s * NPAD;
        const float* bb = (s == 0) ? b1 : (s == 1) ? b2 : b3;
        bo[j] = (q < C4) ? bb[qmap(q)] : 0.f;
    }
}

// ---------------- fused conv1d(k=4,s=2,pad 1,1) [+ graph block] ----------------
// INM 0: stage from f32 (input (B,F,22,3), offset (B,F,22,1)) -> q-order rows
// INM 1: stage from packed bf16 (B,F,88) q-order
// OUTM 0: graph-fused epilogue -> packed bf16 (B,FOUT,88) q-order
// OUTM 1: direct f32 (B,FOUT,66) output (= (B,FOUT,22,3), since q = 3j+c)
template<int FIN, int INM, int OUTM>
__global__ __launch_bounds__(256, 4)
void conv_fused(const float* __restrict__ xf, const float* __restrict__ xoff,
                const unsigned short* __restrict__ xbf,
                const unsigned short* __restrict__ wbf, const float* __restrict__ bias,
                void* __restrict__ yout, GW g)
{
    constexpr int FOUT  = FIN / 2;
    constexpr int NTILE = FOUT / 64;
    __shared__ __align__(16) unsigned char smem[NFR * LROW * 2];   // 27040 B
    unsigned short* Xs = reinterpret_cast<unsigned short*>(smem);
    float*          Yt = reinterpret_cast<float*>(smem);

    const int tid = threadIdx.x;
    const int b   = blockIdx.x / NTILE;
    const int fo0 = (blockIdx.x - b * NTILE) * 64;
    const int gf0 = 2 * fo0 - 1;

    // ---------------- stage X tile: 2 threads per frame, wide unrolled loads ----------------
    {
        const int fgrp = tid >> 1, gg = tid & 1;
#pragma unroll
        for (int cc = 0; cc < 2; ++cc) {
            const int lf = cc * 128 + fgrp;
            if (lf < NFR) {
                const int gf  = gf0 + lf;
                const int gfc = min(max(gf, 0), FIN - 1);
                const bool inb = (gf == gfc);
                unsigned short* dst = Xs + lf * LROW;
                if (INM == 0) {
                    const float2* srcN = reinterpret_cast<const float2*>(xf + ((size_t)b * FIN + gfc) * 66);
                    const float2* srcE = reinterpret_cast<const float2*>(xoff + ((size_t)b * FIN + gfc) * 22);
#pragma unroll
                    for (int i2 = 0; i2 < 17; ++i2) {
                        const int idx = 2 * i2 + gg;
                        if (idx < 33) {
                            const float2 v = srcN[idx];
                            unsigned pk = (unsigned)f2bf(v.x) | ((unsigned)f2bf(v.y) << 16);
                            pk = inb ? pk : 0u;
                            *reinterpret_cast<unsigned*>(dst + 2 * idx) = pk;
                        }
                    }
#pragma unroll
                    for (int i2 = 0; i2 < 6; ++i2) {
                        const int idx = 2 * i2 + gg;
                        if (idx < 11) {
                            const float2 v = srcE[idx];
                            unsigned pk = (unsigned)f2bf(v.x) | ((unsigned)f2bf(v.y) << 16);
                            pk = inb ? pk : 0u;
                            *reinterpret_cast<unsigned*>(dst + 66 + 2 * idx) = pk;
                        }
                    }
                } else {
                    const uintx4* src = reinterpret_cast<const uintx4*>(xbf + ((size_t)b * FIN + gfc) * C4);
                    const uintx4 zero = {0u, 0u, 0u, 0u};
#pragma unroll
                    for (int i2 = 0; i2 < 6; ++i2) {
                        const int idx = 2 * i2 + gg;
                        if (idx < 11) {
                            uintx4 v = src[idx];
                            if (!inb) v = zero;
                            *reinterpret_cast<uintx4*>(dst + 8 * idx) = v;
                        }
                    }
                }
            }
        }
    }
    __syncthreads();

    // ---------------- K-loop: wave = (m-half 32 rows) x (n-half 48 cols) ----------------
    const int wid = tid >> 6, lane = tid & 63;
    const int l15 = lane & 15, h = lane >> 4;
    const int mhalf = wid >> 1, nhalf = wid & 1;

    floatx4 acc[2][3];
#pragma unroll
    for (int mt = 0; mt < 2; ++mt)
#pragma unroll
        for (int nti = 0; nti < 3; ++nti)
            acc[mt][nti] = (floatx4){0.f, 0.f, 0.f, 0.f};

    const unsigned short* wb = wbf + (size_t)(nhalf * 48 + l15) * KK;

#pragma unroll
    for (int kt = 0; kt < 11; ++kt) {
        const int q   = 4 * kt + h;            // [0,44)
        const int tap = (unsigned)q / 11u;
        const int ci0 = 8 * (q - 11 * tap);
        const int lfb = 2 * l15 + tap;

        short8 afr[2];
#pragma unroll
        for (int mt = 0; mt < 2; ++mt)
            afr[mt] = *reinterpret_cast<const short8*>(
                Xs + (mhalf * 64 + mt * 32 + lfb) * LROW + ci0);

        short8 bfr[3];
#pragma unroll
        for (int nti = 0; nti < 3; ++nti)
            bfr[nti] = *reinterpret_cast<const short8*>(wb + (size_t)nti * 16 * KK + kt * 32 + 8 * h);

#pragma unroll
        for (int mt = 0; mt < 2; ++mt)
#pragma unroll
            for (int nti = 0; nti < 3; ++nti)
                acc[mt][nti] = __builtin_amdgcn_mfma_f32_16x16x32_bf16(
                    afr[mt], bfr[nti], acc[mt][nti], 0, 0, 0);
    }

    // ---------------- epilogue ----------------
    if (OUTM == 1) {
        float* yo = reinterpret_cast<float*>(yout);
#pragma unroll
        for (int mt = 0; mt < 2; ++mt)
#pragma unroll
            for (int nti = 0; nti < 3; ++nti) {
                const int co = nhalf * 48 + nti * 16 + l15;
                if (co < 66) {          // node channels only; q = 3j+c is the output index
                    const float bi = bias[co];
#pragma unroll
                    for (int r = 0; r < 4; ++r) {
                        const int m = fo0 + mhalf * 32 + mt * 16 + 4 * h + r;
                        yo[(size_t)(b * FOUT + m) * 66 + co] = acc[mt][nti][r] + bi;
                    }
                }
            }
        return;
    }

    // graph-fused: acc -> LDS Ytile (f32, stride 101)
    __syncthreads();   // all X reads done before overwrite
#pragma unroll
    for (int mt = 0; mt < 2; ++mt)
#pragma unroll
        for (int nti = 0; nti < 3; ++nti) {
            const int co = nhalf * 48 + nti * 16 + l15;
            const float bi = bias[co];
#pragma unroll
            for (int r = 0; r < 4; ++r) {
                const int row = mhalf * 32 + mt * 16 + 4 * h + r;
                Yt[row * YROW + co] = acc[mt][nti][r] + bi;
            }
        }
    __syncthreads();

    // graph block: thread = (row = tid&63, joint-group = tid>>6)
    {
        const int row = tid & 63, grp = tid >> 6;
        const float* yr = Yt + row * YROW;

        float n2n[9], n2nb[3], e2we[3], e2wn[9], e2nb[3], newn[3], lin[18], linb[3];
#pragma unroll
        for (int i = 0; i < 9;  ++i) n2n[i]  = g.n2n_w[i];
#pragma unroll
        for (int i = 0; i < 3;  ++i) n2nb[i] = g.n2n_b[i];
#pragma unroll
        for (int i = 0; i < 3;  ++i) e2we[i] = g.e2n_we[i];
#pragma unroll
        for (int i = 0; i < 9;  ++i) e2wn[i] = g.e2n_wn[i];
#pragma unroll
        for (int i = 0; i < 3;  ++i) e2nb[i] = g.e2n_b[i];
#pragma unroll
        for (int i = 0; i < 3;  ++i) newn[i] = g.n2e_wn[i];
        const float newe = g.n2e_we[0];
        const float neb  = g.n2e_b[0];
#pragma unroll
        for (int i = 0; i < 18; ++i) lin[i]  = g.lin_w[i];
#pragma unroll
        for (int i = 0; i < 3;  ++i) linb[i] = g.lin_b[i];

        unsigned short* xout = reinterpret_cast<unsigned short*>(yout);
        const size_t orow = ((size_t)b * FOUT + fo0 + row) * C4;

#pragma unroll
        for (int i = 0; i < Jn; ++i) {
            if (i / 6 != grp) continue;      // wave-uniform
            float an0 = 0.f, an1 = 0.f, an2 = 0.f, ae = 0.f;
#pragma unroll
            for (int j = 1; j < Jn; ++j) {
                if (TOPc[j] == i) {
                    an0 += yr[3 * j]; an1 += yr[3 * j + 1];
                    an2 += yr[3 * j + 2]; ae += yr[66 + j];
                }
            }
            const float s0 = yr[3 * i], s1 = yr[3 * i + 1], s2 = yr[3 * i + 2], se = yr[66 + i];
            float f1[3], f2[3];
#pragma unroll
            for (int c = 0; c < 3; ++c) {
                f1[c] = an0 * n2n[c] + an1 * n2n[3 + c] + an2 * n2n[6 + c] + n2nb[c];
                f2[c] = ae * e2we[c] + s0 * e2wn[c] + s1 * e2wn[3 + c] + s2 * e2wn[6 + c] + e2nb[c];
            }
            float p0 = 0.f, p1 = 0.f, p2 = 0.f;
            if (i > 0) {
                const int p = TOPc[i];
                p0 = yr[3 * p]; p1 = yr[3 * p + 1]; p2 = yr[3 * p + 2];
            }
            const float ne = p0 * newn[0] + p1 * newn[1] + p2 * newn[2] + se * newe + neb;

            float o[3];
#pragma unroll
            for (int c = 0; c < 3; ++c)
                o[c] = f1[0] * lin[0 + c] + f1[1] * lin[3 + c] + f1[2] * lin[6 + c]
                     + f2[0] * lin[9 + c] + f2[1] * lin[12 + c] + f2[2] * lin[15 + c] + linb[c];

            xout[orow + 3 * i]     = f2bf(o[0]);
            xout[orow + 3 * i + 1] = f2bf(o[1]);
            xout[orow + 3 * i + 2] = f2bf(o[2]);
            xout[orow + 66 + i]    = f2bf(ne);
        }
    }
}

extern "C" void kernel_launch(void* const* d_in, const int* in_sizes, int n_in,
                              void* d_out, int out_size, void* d_ws, size_t ws_size,
                              hipStream_t stream)
{
    (void)n_in; (void)out_size; (void)ws_size;

    const float* input  = (const float*)d_in[0];
    const float* offset = (const float*)d_in[1];
    const float* c1w = (const float*)d_in[2]; const float* c1b = (const float*)d_in[3];
    const float* c2w = (const float*)d_in[4]; const float* c2b = (const float*)d_in[5];
    const float* c3w = (const float*)d_in[6]; const float* c3b = (const float*)d_in[7];

    GW g1 { (const float*)d_in[8],  (const float*)d_in[9],  (const float*)d_in[10],
            (const float*)d_in[11], (const float*)d_in[12], (const float*)d_in[13],
            (const float*)d_in[14], (const float*)d_in[15], (const float*)d_in[16],
            (const float*)d_in[17] };
    GW g2 { (const float*)d_in[18], (const float*)d_in[19], (const float*)d_in[20],
            (const float*)d_in[21], (const float*)d_in[22], (const float*)d_in[23],
            (const float*)d_in[24], (const float*)d_in[25], (const float*)d_in[26],
            (const float*)d_in[27] };

    const int B = in_sizes[0] / (2048 * Jn * 3);   // 128

    unsigned short* wbf = (unsigned short*)d_ws;                  // 3*[96][352] bf16
    float* pb = (float*)(wbf + (size_t)3 * NPAD * KK);            // 3*[96] f32 permuted bias
    unsigned short* X1 = (unsigned short*)(pb + 3 * NPAD);        // (B,1024,88) bf16
    unsigned short* X2 = X1 + (size_t)B * 1024 * C4;              // (B, 512,88) bf16

    {
        const int tot = 3 * NPAD * KK + 3 * NPAD;
        prep_weights<<<(tot + 255) / 256, 256, 0, stream>>>(c1w, c2w, c3w, c1b, c2b, c3b, wbf, pb);
    }

    conv_fused<2048, 0, 0><<<B * 16, 256, 0, stream>>>(input, offset, nullptr,
                                                       wbf, pb, X1, g1);
    conv_fused<1024, 1, 0><<<B * 8, 256, 0, stream>>>(nullptr, nullptr, X1,
                                                      wbf + NPAD * KK, pb + NPAD, X2, g2);
    conv_fused<512, 1, 1><<<B * 4, 256, 0, stream>>>(nullptr, nullptr, X2,
                                                     wbf + 2 * NPAD * KK, pb + 2 * NPAD, d_out, g2);
}

// Round 6
// 82.013 us; speedup vs baseline: 1.1057x; 1.1057x over previous
//
#include <hip/hip_runtime.h>

// Encoder_29661044146233 — round 6 (bisection):
//  = round 4 (known-good epilogues, direct global stores)
//  + swizzled MFMA-lane-order B-weights (coalesced 16B/lane loads)
//  + flat contiguous staging (coalesced, clamped non-negative indices)
//  LDS-bounce epilogues from r5 are REVERTED (prime suspect for r5's failure).

static constexpr int Jn   = 22;
static constexpr int C4   = 88;     // q-order: q<66 node(j=q/3,c=q%3), q>=66 edge(j=q-66)
static constexpr int KK   = 352;    // 4 taps * 88  (k = tap*88 + q)
static constexpr int NPAD = 96;
static constexpr int LROW = 104;    // LDS X row stride in ushorts (208 B)
static constexpr int YROW = 101;    // Ytile row stride in floats
static constexpr int NFR  = 130;    // input frames per block (2*64 + 2 halo)
static constexpr int WSWZ = 2 * 11 * 3 * 64 * 8;   // 33792 bf16 elements per conv

typedef __attribute__((ext_vector_type(8))) short    short8;
typedef __attribute__((ext_vector_type(4))) float    floatx4;
typedef __attribute__((ext_vector_type(4))) unsigned uintx4;

__device__ constexpr int TOPc[Jn] = {0,0,1,2,3,4,0,6,7,8,0,10,11,12,12,14,15,16,12,18,19,20};

__device__ __forceinline__ unsigned short f2bf(float f) {
    unsigned u = __builtin_bit_cast(unsigned, f);
    unsigned r = (u + 0x7FFFu + ((u >> 16) & 1u)) >> 16;
    return (unsigned short)r;
}
__device__ __forceinline__ int qmap(int q) {          // q-order -> reference 4j+c channel
    return (q < 66) ? 4 * (q / 3) + (q % 3) : 4 * (q - 66) + 3;
}

struct GW {
    const float *n2n_w, *n2n_b, *e2n_we, *e2n_wn, *e2n_b;
    const float *n2e_wn, *n2e_we, *n2e_b, *lin_w, *lin_b;
};

// ---- prep: weights -> bf16 swizzled MFMA-fragment order [nh][kt][nti][lane][j]
//      element: co = nh*48+nti*16+(lane&15), k = kt*32+8*(lane>>4)+j, both sides q-order ----
__global__ __launch_bounds__(256)
void prep_weights(const float* __restrict__ w1, const float* __restrict__ w2,
                  const float* __restrict__ w3,
                  const float* __restrict__ b1, const float* __restrict__ b2,
                  const float* __restrict__ b3,
                  unsigned short* __restrict__ wo, float* __restrict__ bo)
{
    const int i = blockIdx.x * 256 + threadIdx.x;
    if (i < 3 * WSWZ) {
        const int s = i / WSWZ, e = i - s * WSWZ;
        const int j = e & 7, t = e >> 3;
        const int lane = t & 63, t2 = t >> 6;
        const int nti = t2 % 3, t3 = t2 / 3;
        const int kt = t3 % 11, nh = t3 / 11;
        const int co = nh * 48 + nti * 16 + (lane & 15);
        const int k  = kt * 32 + 8 * (lane >> 4) + j;
        const int tap = k / C4, q = k - tap * C4;
        const float* w = (s == 0) ? w1 : (s == 1) ? w2 : w3;
        float v = 0.f;
        if (co < C4) v = w[((size_t)qmap(co) * C4 + qmap(q)) * 4 + tap];
        wo[i] = f2bf(v);
    } else if (i < 3 * WSWZ + 3 * NPAD) {
        const int jj = i - 3 * WSWZ;
        const int s = jj / NPAD, q = jj - s * NPAD;
        const float* bb = (s == 0) ? b1 : (s == 1) ? b2 : b3;
        bo[jj] = (q < C4) ? bb[qmap(q)] : 0.f;
    }
}

// ---------------- fused conv1d(k=4,s=2,pad 1,1) [+ graph block] ----------------
// INM 0: stage from f32 (input (B,F,22,3), offset (B,F,22,1)) -> q-order rows
// INM 1: stage from packed bf16 (B,F,88) q-order
// OUTM 0: graph-fused epilogue -> packed bf16 (B,FOUT,88) q-order (direct stores)
// OUTM 1: direct f32 (B,FOUT,66) output
template<int FIN, int INM, int OUTM>
__global__ __launch_bounds__(256, 4)
void conv_fused(const float* __restrict__ xf, const float* __restrict__ xoff,
                const unsigned short* __restrict__ xbf,
                const unsigned short* __restrict__ bwz, const float* __restrict__ bias,
                void* __restrict__ yout, GW g)
{
    constexpr int FOUT  = FIN / 2;
    constexpr int NTILE = FOUT / 64;
    __shared__ __align__(16) unsigned char smem[NFR * LROW * 2];   // 27040 B
    unsigned short* Xs = reinterpret_cast<unsigned short*>(smem);
    unsigned*       Xw = reinterpret_cast<unsigned*>(smem);
    float*          Yt = reinterpret_cast<float*>(smem);

    const int tid = threadIdx.x;
    const int b   = blockIdx.x / NTILE;
    const int fo0 = (blockIdx.x - b * NTILE) * 64;
    const int gf0 = 2 * fo0 - 1;

    // ---------------- stage X tile: flat contiguous coalesced loads ----------------
    if (INM == 0) {
        const float2* xn2 = reinterpret_cast<const float2*>(xf)   + (size_t)b * FIN * 33;
        const float2* xe2 = reinterpret_cast<const float2*>(xoff) + (size_t)b * FIN * 11;
        // node: 130 frames * 33 float2 (contiguous for interior frames)
#pragma unroll
        for (int it = 0; it < 17; ++it) {
            const int idx = tid + it * 256;
            if (idx < NFR * 33) {
                const int lf = idx / 33, q2 = idx - lf * 33;
                const int gf = gf0 + lf;
                const int gfc = min(max(gf, 0), FIN - 1);
                const float2 v = xn2[gfc * 33 + q2];
                unsigned pk = (unsigned)f2bf(v.x) | ((unsigned)f2bf(v.y) << 16);
                pk = (gf == gfc) ? pk : 0u;
                Xw[lf * 52 + q2] = pk;
            }
        }
        // edge: 130 * 11 float2
#pragma unroll
        for (int it = 0; it < 6; ++it) {
            const int idx = tid + it * 256;
            if (idx < NFR * 11) {
                const int lf = idx / 11, q2 = idx - lf * 11;
                const int gf = gf0 + lf;
                const int gfc = min(max(gf, 0), FIN - 1);
                const float2 v = xe2[gfc * 11 + q2];
                unsigned pk = (unsigned)f2bf(v.x) | ((unsigned)f2bf(v.y) << 16);
                pk = (gf == gfc) ? pk : 0u;
                Xw[lf * 52 + 33 + q2] = pk;
            }
        }
    } else {
        const uintx4* xsrc = reinterpret_cast<const uintx4*>(xbf) + (size_t)b * FIN * 11;
#pragma unroll
        for (int it = 0; it < 6; ++it) {
            const int idx = tid + it * 256;
            if (idx < NFR * 11) {
                const int lf = idx / 11, qq = idx - lf * 11;
                const int gf = gf0 + lf;
                const int gfc = min(max(gf, 0), FIN - 1);
                uintx4 v = xsrc[gfc * 11 + qq];
                if (gf != gfc) v = (uintx4){0u, 0u, 0u, 0u};
                *reinterpret_cast<uintx4*>(Xs + lf * LROW + qq * 8) = v;
            }
        }
    }
    __syncthreads();

    // ---------------- K-loop: wave = (m-half 32 rows) x (n-half 48 cols) ----------------
    const int wid = tid >> 6, lane = tid & 63;
    const int l15 = lane & 15, h = lane >> 4;
    const int mhalf = wid >> 1, nhalf = wid & 1;

    floatx4 acc[2][3];
#pragma unroll
    for (int mt = 0; mt < 2; ++mt)
#pragma unroll
        for (int nti = 0; nti < 3; ++nti)
            acc[mt][nti] = (floatx4){0.f, 0.f, 0.f, 0.f};

    const unsigned short* wb = bwz + ((size_t)nhalf * 33 * 64 + lane) * 8;

#pragma unroll
    for (int kt = 0; kt < 11; ++kt) {
        const int q   = 4 * kt + h;            // [0,44)
        const int tap = (unsigned)q / 11u;
        const int ci0 = 8 * (q - 11 * tap);
        const int lfb = 2 * l15 + tap;

        short8 afr[2];
#pragma unroll
        for (int mt = 0; mt < 2; ++mt)
            afr[mt] = *reinterpret_cast<const short8*>(
                Xs + (mhalf * 64 + mt * 32 + lfb) * LROW + ci0);

        short8 bfr[3];
#pragma unroll
        for (int nti = 0; nti < 3; ++nti)
            bfr[nti] = *reinterpret_cast<const short8*>(wb + (size_t)(kt * 3 + nti) * 64 * 8);

#pragma unroll
        for (int mt = 0; mt < 2; ++mt)
#pragma unroll
            for (int nti = 0; nti < 3; ++nti)
                acc[mt][nti] = __builtin_amdgcn_mfma_f32_16x16x32_bf16(
                    afr[mt], bfr[nti], acc[mt][nti], 0, 0, 0);
    }

    // ---------------- epilogue (r4 verbatim: direct global stores) ----------------
    if (OUTM == 1) {
        float* yo = reinterpret_cast<float*>(yout);
#pragma unroll
        for (int mt = 0; mt < 2; ++mt)
#pragma unroll
            for (int nti = 0; nti < 3; ++nti) {
                const int co = nhalf * 48 + nti * 16 + l15;
                if (co < 66) {
                    const float bi = bias[co];
#pragma unroll
                    for (int r = 0; r < 4; ++r) {
                        const int m = fo0 + mhalf * 32 + mt * 16 + 4 * h + r;
                        yo[(size_t)(b * FOUT + m) * 66 + co] = acc[mt][nti][r] + bi;
                    }
                }
            }
        return;
    }

    // graph-fused: acc -> LDS Ytile (f32, stride 101)
    __syncthreads();   // all X reads done before overwrite
#pragma unroll
    for (int mt = 0; mt < 2; ++mt)
#pragma unroll
        for (int nti = 0; nti < 3; ++nti) {
            const int co = nhalf * 48 + nti * 16 + l15;
            const float bi = bias[co];
#pragma unroll
            for (int r = 0; r < 4; ++r) {
                const int row = mhalf * 32 + mt * 16 + 4 * h + r;
                Yt[row * YROW + co] = acc[mt][nti][r] + bi;
            }
        }
    __syncthreads();

    // graph block: thread = (row = tid&63, joint-group = tid>>6); direct stores
    {
        const int row = tid & 63, grp = tid >> 6;
        const float* yr = Yt + row * YROW;

        float n2n[9], n2nb[3], e2we[3], e2wn[9], e2nb[3], newn[3], lin[18], linb[3];
#pragma unroll
        for (int i = 0; i < 9;  ++i) n2n[i]  = g.n2n_w[i];
#pragma unroll
        for (int i = 0; i < 3;  ++i) n2nb[i] = g.n2n_b[i];
#pragma unroll
        for (int i = 0; i < 3;  ++i) e2we[i] = g.e2n_we[i];
#pragma unroll
        for (int i = 0; i < 9;  ++i) e2wn[i] = g.e2n_wn[i];
#pragma unroll
        for (int i = 0; i < 3;  ++i) e2nb[i] = g.e2n_b[i];
#pragma unroll
        for (int i = 0; i < 3;  ++i) newn[i] = g.n2e_wn[i];
        const float newe = g.n2e_we[0];
        const float neb  = g.n2e_b[0];
#pragma unroll
        for (int i = 0; i < 18; ++i) lin[i]  = g.lin_w[i];
#pragma unroll
        for (int i = 0; i < 3;  ++i) linb[i] = g.lin_b[i];

        unsigned short* xout = reinterpret_cast<unsigned short*>(yout);
        const size_t orow = ((size_t)b * FOUT + fo0 + row) * C4;

#pragma unroll
        for (int i = 0; i < Jn; ++i) {
            if (i / 6 != grp) continue;      // wave-uniform
            float an0 = 0.f, an1 = 0.f, an2 = 0.f, ae = 0.f;
#pragma unroll
            for (int j = 1; j < Jn; ++j) {
                if (TOPc[j] == i) {
                    an0 += yr[3 * j]; an1 += yr[3 * j + 1];
                    an2 += yr[3 * j + 2]; ae += yr[66 + j];
                }
            }
            const float s0 = yr[3 * i], s1 = yr[3 * i + 1], s2 = yr[3 * i + 2], se = yr[66 + i];
            float f1[3], f2[3];
#pragma unroll
            for (int c = 0; c < 3; ++c) {
                f1[c] = an0 * n2n[c] + an1 * n2n[3 + c] + an2 * n2n[6 + c] + n2nb[c];
                f2[c] = ae * e2we[c] + s0 * e2wn[c] + s1 * e2wn[3 + c] + s2 * e2wn[6 + c] + e2nb[c];
            }
            float p0 = 0.f, p1 = 0.f, p2 = 0.f;
            if (i > 0) {
                const int p = TOPc[i];
                p0 = yr[3 * p]; p1 = yr[3 * p + 1]; p2 = yr[3 * p + 2];
            }
            const float ne = p0 * newn[0] + p1 * newn[1] + p2 * newn[2] + se * newe + neb;

            float o[3];
#pragma unroll
            for (int c = 0; c < 3; ++c)
                o[c] = f1[0] * lin[0 + c] + f1[1] * lin[3 + c] + f1[2] * lin[6 + c]
                     + f2[0] * lin[9 + c] + f2[1] * lin[12 + c] + f2[2] * lin[15 + c] + linb[c];

            xout[orow + 3 * i]     = f2bf(o[0]);
            xout[orow + 3 * i + 1] = f2bf(o[1]);
            xout[orow + 3 * i + 2] = f2bf(o[2]);
            xout[orow + 66 + i]    = f2bf(ne);
        }
    }
}

extern "C" void kernel_launch(void* const* d_in, const int* in_sizes, int n_in,
                              void* d_out, int out_size, void* d_ws, size_t ws_size,
                              hipStream_t stream)
{
    (void)n_in; (void)out_size; (void)ws_size;

    const float* input  = (const float*)d_in[0];
    const float* offset = (const float*)d_in[1];
    const float* c1w = (const float*)d_in[2]; const float* c1b = (const float*)d_in[3];
    const float* c2w = (const float*)d_in[4]; const float* c2b = (const float*)d_in[5];
    const float* c3w = (const float*)d_in[6]; const float* c3b = (const float*)d_in[7];

    GW g1 { (const float*)d_in[8],  (const float*)d_in[9],  (const float*)d_in[10],
            (const float*)d_in[11], (const float*)d_in[12], (const float*)d_in[13],
            (const float*)d_in[14], (const float*)d_in[15], (const float*)d_in[16],
            (const float*)d_in[17] };
    GW g2 { (const float*)d_in[18], (const float*)d_in[19], (const float*)d_in[20],
            (const float*)d_in[21], (const float*)d_in[22], (const float*)d_in[23],
            (const float*)d_in[24], (const float*)d_in[25], (const float*)d_in[26],
            (const float*)d_in[27] };

    const int B = in_sizes[0] / (2048 * Jn * 3);   // 128

    unsigned short* wbf = (unsigned short*)d_ws;                  // 3*33792 bf16 swizzled
    float* pb = (float*)(wbf + (size_t)3 * WSWZ);                 // 3*[96] f32 permuted bias
    unsigned short* X1 = (unsigned short*)(pb + 3 * NPAD);        // (B,1024,88) bf16
    unsigned short* X2 = X1 + (size_t)B * 1024 * C4;              // (B, 512,88) bf16

    {
        const int tot = 3 * WSWZ + 3 * NPAD;
        prep_weights<<<(tot + 255) / 256, 256, 0, stream>>>(c1w, c2w, c3w, c1b, c2b, c3b, wbf, pb);
    }

    conv_fused<2048, 0, 0><<<B * 16, 256, 0, stream>>>(input, offset, nullptr,
                                                       wbf, pb, X1, g1);
    conv_fused<1024, 1, 0><<<B * 8, 256, 0, stream>>>(nullptr, nullptr, X1,
                                                      wbf + WSWZ, pb + NPAD, X2, g2);
    conv_fused<512, 1, 1><<<B * 4, 256, 0, stream>>>(nullptr, nullptr, X2,
                                                     wbf + 2 * WSWZ, pb + 2 * NPAD, d_out, g2);
}

// Round 9
// 78.501 us; speedup vs baseline: 1.1551x; 1.0447x over previous
//
#include <hip/hip_runtime.h>

// Encoder_29661044146233 — round 9 (single-variable bisect vs r6):
//  = round 6 byte-identical (LROW=104, per-iteration conv2/3 staging, direct-store
//    epilogues, swizzled weights, q-order channels)
//  + ONLY change: conv1 staging is two-phase (all 23 float2 loads issued clamped &
//    unconditional into registers, sched_barrier(0), then convert+write to LDS).
//  global_load_lds abandoned (r7/r8 failures undiagnosed -> off the suspect list).

static constexpr int Jn   = 22;
static constexpr int C4   = 88;     // q-order: q<66 node(j=q/3,c=q%3), q>=66 edge(j=q-66)
static constexpr int KK   = 352;    // 4 taps * 88  (k = tap*88 + q)
static constexpr int NPAD = 96;
static constexpr int LROW = 104;    // LDS X row stride in ushorts (208 B)
static constexpr int YROW = 101;    // Ytile row stride in floats
static constexpr int NFR  = 130;    // input frames per block (2*64 + 2 halo)
static constexpr int WSWZ = 2 * 11 * 3 * 64 * 8;   // 33792 bf16 elements per conv

typedef __attribute__((ext_vector_type(8))) short    short8;
typedef __attribute__((ext_vector_type(4))) float    floatx4;
typedef __attribute__((ext_vector_type(4))) unsigned uintx4;

__device__ constexpr int TOPc[Jn] = {0,0,1,2,3,4,0,6,7,8,0,10,11,12,12,14,15,16,12,18,19,20};

__device__ __forceinline__ unsigned short f2bf(float f) {
    unsigned u = __builtin_bit_cast(unsigned, f);
    unsigned r = (u + 0x7FFFu + ((u >> 16) & 1u)) >> 16;
    return (unsigned short)r;
}
__device__ __forceinline__ int qmap(int q) {          // q-order -> reference 4j+c channel
    return (q < 66) ? 4 * (q / 3) + (q % 3) : 4 * (q - 66) + 3;
}

struct GW {
    const float *n2n_w, *n2n_b, *e2n_we, *e2n_wn, *e2n_b;
    const float *n2e_wn, *n2e_we, *n2e_b, *lin_w, *lin_b;
};

// ---- prep: weights -> bf16 swizzled MFMA-fragment order [nh][kt][nti][lane][j] ----
__global__ __launch_bounds__(256)
void prep_weights(const float* __restrict__ w1, const float* __restrict__ w2,
                  const float* __restrict__ w3,
                  const float* __restrict__ b1, const float* __restrict__ b2,
                  const float* __restrict__ b3,
                  unsigned short* __restrict__ wo, float* __restrict__ bo)
{
    const int i = blockIdx.x * 256 + threadIdx.x;
    if (i < 3 * WSWZ) {
        const int s = i / WSWZ, e = i - s * WSWZ;
        const int j = e & 7, t = e >> 3;
        const int lane = t & 63, t2 = t >> 6;
        const int nti = t2 % 3, t3 = t2 / 3;
        const int kt = t3 % 11, nh = t3 / 11;
        const int co = nh * 48 + nti * 16 + (lane & 15);
        const int k  = kt * 32 + 8 * (lane >> 4) + j;
        const int tap = k / C4, q = k - tap * C4;
        const float* w = (s == 0) ? w1 : (s == 1) ? w2 : w3;
        float v = 0.f;
        if (co < C4) v = w[((size_t)qmap(co) * C4 + qmap(q)) * 4 + tap];
        wo[i] = f2bf(v);
    } else if (i < 3 * WSWZ + 3 * NPAD) {
        const int jj = i - 3 * WSWZ;
        const int s = jj / NPAD, q = jj - s * NPAD;
        const float* bb = (s == 0) ? b1 : (s == 1) ? b2 : b3;
        bo[jj] = (q < C4) ? bb[qmap(q)] : 0.f;
    }
}

// ---------------- fused conv1d(k=4,s=2,pad 1,1) [+ graph block] ----------------
// INM 0: stage from f32 (input (B,F,22,3), offset (B,F,22,1)) -> q-order rows
// INM 1: stage from packed bf16 (B,F,88) q-order
// OUTM 0: graph-fused epilogue -> packed bf16 (B,FOUT,88) q-order (direct stores)
// OUTM 1: direct f32 (B,FOUT,66) output
template<int FIN, int INM, int OUTM>
__global__ __launch_bounds__(256, 4)
void conv_fused(const float* __restrict__ xf, const float* __restrict__ xoff,
                const unsigned short* __restrict__ xbf,
                const unsigned short* __restrict__ bwz, const float* __restrict__ bias,
                void* __restrict__ yout, GW g)
{
    constexpr int FOUT  = FIN / 2;
    constexpr int NTILE = FOUT / 64;
    __shared__ __align__(16) unsigned char smem[NFR * LROW * 2];   // 27040 B
    unsigned short* Xs = reinterpret_cast<unsigned short*>(smem);
    unsigned*       Xw = reinterpret_cast<unsigned*>(smem);
    float*          Yt = reinterpret_cast<float*>(smem);

    const int tid = threadIdx.x;
    const int b   = blockIdx.x / NTILE;
    const int fo0 = (blockIdx.x - b * NTILE) * 64;
    const int gf0 = 2 * fo0 - 1;

    // ---------------- stage X tile ----------------
    if (INM == 0) {
        // phase 1: issue ALL loads (clamped index, unconditional) into registers
        float2 tN[17], tE[6];
        const float2* xn2 = reinterpret_cast<const float2*>(xf)   + (size_t)b * FIN * 33;
        const float2* xe2 = reinterpret_cast<const float2*>(xoff) + (size_t)b * FIN * 11;
#pragma unroll
        for (int it = 0; it < 17; ++it) {
            const int idx = min(tid + it * 256, NFR * 33 - 1);
            const int lf = idx / 33, q2 = idx - lf * 33;
            const int gfc = min(max(gf0 + lf, 0), FIN - 1);
            tN[it] = xn2[(size_t)gfc * 33 + q2];
        }
#pragma unroll
        for (int it = 0; it < 6; ++it) {
            const int idx = min(tid + it * 256, NFR * 11 - 1);
            const int lf = idx / 11, q2 = idx - lf * 11;
            const int gfc = min(max(gf0 + lf, 0), FIN - 1);
            tE[it] = xe2[(size_t)gfc * 11 + q2];
        }
        __builtin_amdgcn_sched_barrier(0);   // keep the load cluster ahead of the writes
        // phase 2: convert + write (r6's writes verbatim)
#pragma unroll
        for (int it = 0; it < 17; ++it) {
            const int idx = tid + it * 256;
            if (idx < NFR * 33) {
                const int lf = idx / 33, q2 = idx - lf * 33;
                const int gf = gf0 + lf;
                unsigned pk = (unsigned)f2bf(tN[it].x) | ((unsigned)f2bf(tN[it].y) << 16);
                pk = ((unsigned)gf < (unsigned)FIN) ? pk : 0u;
                Xw[lf * 52 + q2] = pk;
            }
        }
#pragma unroll
        for (int it = 0; it < 6; ++it) {
            const int idx = tid + it * 256;
            if (idx < NFR * 11) {
                const int lf = idx / 11, q2 = idx - lf * 11;
                const int gf = gf0 + lf;
                unsigned pk = (unsigned)f2bf(tE[it].x) | ((unsigned)f2bf(tE[it].y) << 16);
                pk = ((unsigned)gf < (unsigned)FIN) ? pk : 0u;
                Xw[lf * 52 + 33 + q2] = pk;
            }
        }
    } else {
        // r6 verbatim: per-iteration uint4 staging loop
        const uintx4* xsrc = reinterpret_cast<const uintx4*>(xbf) + (size_t)b * FIN * 11;
#pragma unroll
        for (int it = 0; it < 6; ++it) {
            const int idx = tid + it * 256;
            if (idx < NFR * 11) {
                const int lf = idx / 11, qq = idx - lf * 11;
                const int gf = gf0 + lf;
                const int gfc = min(max(gf, 0), FIN - 1);
                uintx4 v = xsrc[gfc * 11 + qq];
                if (gf != gfc) v = (uintx4){0u, 0u, 0u, 0u};
                *reinterpret_cast<uintx4*>(Xs + lf * LROW + qq * 8) = v;
            }
        }
    }
    __syncthreads();

    // ---------------- K-loop: wave = (m-half 32 rows) x (n-half 48 cols) ----------------
    const int wid = tid >> 6, lane = tid & 63;
    const int l15 = lane & 15, h = lane >> 4;
    const int mhalf = wid >> 1, nhalf = wid & 1;

    floatx4 acc[2][3];
#pragma unroll
    for (int mt = 0; mt < 2; ++mt)
#pragma unroll
        for (int nti = 0; nti < 3; ++nti)
            acc[mt][nti] = (floatx4){0.f, 0.f, 0.f, 0.f};

    const unsigned short* wb = bwz + ((size_t)nhalf * 33 * 64 + lane) * 8;

#pragma unroll
    for (int kt = 0; kt < 11; ++kt) {
        const int q   = 4 * kt + h;            // [0,44)
        const int tap = (unsigned)q / 11u;
        const int ci0 = 8 * (q - 11 * tap);
        const int lfb = 2 * l15 + tap;

        short8 afr[2];
#pragma unroll
        for (int mt = 0; mt < 2; ++mt)
            afr[mt] = *reinterpret_cast<const short8*>(
                Xs + (mhalf * 64 + mt * 32 + lfb) * LROW + ci0);

        short8 bfr[3];
#pragma unroll
        for (int nti = 0; nti < 3; ++nti)
            bfr[nti] = *reinterpret_cast<const short8*>(wb + (size_t)(kt * 3 + nti) * 64 * 8);

#pragma unroll
        for (int mt = 0; mt < 2; ++mt)
#pragma unroll
            for (int nti = 0; nti < 3; ++nti)
                acc[mt][nti] = __builtin_amdgcn_mfma_f32_16x16x32_bf16(
                    afr[mt], bfr[nti], acc[mt][nti], 0, 0, 0);
    }

    // ---------------- epilogue (r6 verbatim: direct global stores) ----------------
    if (OUTM == 1) {
        float* yo = reinterpret_cast<float*>(yout);
#pragma unroll
        for (int mt = 0; mt < 2; ++mt)
#pragma unroll
            for (int nti = 0; nti < 3; ++nti) {
                const int co = nhalf * 48 + nti * 16 + l15;
                if (co < 66) {
                    const float bi = bias[co];
#pragma unroll
                    for (int r = 0; r < 4; ++r) {
                        const int m = fo0 + mhalf * 32 + mt * 16 + 4 * h + r;
                        yo[(size_t)(b * FOUT + m) * 66 + co] = acc[mt][nti][r] + bi;
                    }
                }
            }
        return;
    }

    // graph-fused: acc -> LDS Ytile (f32, stride 101)
    __syncthreads();   // all X reads done before overwrite
#pragma unroll
    for (int mt = 0; mt < 2; ++mt)
#pragma unroll
        for (int nti = 0; nti < 3; ++nti) {
            const int co = nhalf * 48 + nti * 16 + l15;
            const float bi = bias[co];
#pragma unroll
            for (int r = 0; r < 4; ++r) {
                const int row = mhalf * 32 + mt * 16 + 4 * h + r;
                Yt[row * YROW + co] = acc[mt][nti][r] + bi;
            }
        }
    __syncthreads();

    // graph block: thread = (row = tid&63, joint-group = tid>>6); direct stores
    {
        const int row = tid & 63, grp = tid >> 6;
        const float* yr = Yt + row * YROW;

        float n2n[9], n2nb[3], e2we[3], e2wn[9], e2nb[3], newn[3], lin[18], linb[3];
#pragma unroll
        for (int i = 0; i < 9;  ++i) n2n[i]  = g.n2n_w[i];
#pragma unroll
        for (int i = 0; i < 3;  ++i) n2nb[i] = g.n2n_b[i];
#pragma unroll
        for (int i = 0; i < 3;  ++i) e2we[i] = g.e2n_we[i];
#pragma unroll
        for (int i = 0; i < 9;  ++i) e2wn[i] = g.e2n_wn[i];
#pragma unroll
        for (int i = 0; i < 3;  ++i) e2nb[i] = g.e2n_b[i];
#pragma unroll
        for (int i = 0; i < 3;  ++i) newn[i] = g.n2e_wn[i];
        const float newe = g.n2e_we[0];
        const float neb  = g.n2e_b[0];
#pragma unroll
        for (int i = 0; i < 18; ++i) lin[i]  = g.lin_w[i];
#pragma unroll
        for (int i = 0; i < 3;  ++i) linb[i] = g.lin_b[i];

        unsigned short* xout = reinterpret_cast<unsigned short*>(yout);
        const size_t orow = ((size_t)b * FOUT + fo0 + row) * C4;

#pragma unroll
        for (int i = 0; i < Jn; ++i) {
            if (i / 6 != grp) continue;      // wave-uniform
            float an0 = 0.f, an1 = 0.f, an2 = 0.f, ae = 0.f;
#pragma unroll
            for (int j = 1; j < Jn; ++j) {
                if (TOPc[j] == i) {
                    an0 += yr[3 * j]; an1 += yr[3 * j + 1];
                    an2 += yr[3 * j + 2]; ae += yr[66 + j];
                }
            }
            const float s0 = yr[3 * i], s1 = yr[3 * i + 1], s2 = yr[3 * i + 2], se = yr[66 + i];
            float f1[3], f2[3];
#pragma unroll
            for (int c = 0; c < 3; ++c) {
                f1[c] = an0 * n2n[c] + an1 * n2n[3 + c] + an2 * n2n[6 + c] + n2nb[c];
                f2[c] = ae * e2we[c] + s0 * e2wn[c] + s1 * e2wn[3 + c] + s2 * e2wn[6 + c] + e2nb[c];
            }
            float p0 = 0.f, p1 = 0.f, p2 = 0.f;
            if (i > 0) {
                const int p = TOPc[i];
                p0 = yr[3 * p]; p1 = yr[3 * p + 1]; p2 = yr[3 * p + 2];
            }
            const float ne = p0 * newn[0] + p1 * newn[1] + p2 * newn[2] + se * newe + neb;

            float o[3];
#pragma unroll
            for (int c = 0; c < 3; ++c)
                o[c] = f1[0] * lin[0 + c] + f1[1] * lin[3 + c] + f1[2] * lin[6 + c]
                     + f2[0] * lin[9 + c] + f2[1] * lin[12 + c] + f2[2] * lin[15 + c] + linb[c];

            xout[orow + 3 * i]     = f2bf(o[0]);
            xout[orow + 3 * i + 1] = f2bf(o[1]);
            xout[orow + 3 * i + 2] = f2bf(o[2]);
            xout[orow + 66 + i]    = f2bf(ne);
        }
    }
}

extern "C" void kernel_launch(void* const* d_in, const int* in_sizes, int n_in,
                              void* d_out, int out_size, void* d_ws, size_t ws_size,
                              hipStream_t stream)
{
    (void)n_in; (void)out_size; (void)ws_size;

    const float* input  = (const float*)d_in[0];
    const float* offset = (const float*)d_in[1];
    const float* c1w = (const float*)d_in[2]; const float* c1b = (const float*)d_in[3];
    const float* c2w = (const float*)d_in[4]; const float* c2b = (const float*)d_in[5];
    const float* c3w = (const float*)d_in[6]; const float* c3b = (const float*)d_in[7];

    GW g1 { (const float*)d_in[8],  (const float*)d_in[9],  (const float*)d_in[10],
            (const float*)d_in[11], (const float*)d_in[12], (const float*)d_in[13],
            (const float*)d_in[14], (const float*)d_in[15], (const float*)d_in[16],
            (const float*)d_in[17] };
    GW g2 { (const float*)d_in[18], (const float*)d_in[19], (const float*)d_in[20],
            (const float*)d_in[21], (const float*)d_in[22], (const float*)d_in[23],
            (const float*)d_in[24], (const float*)d_in[25], (const float*)d_in[26],
            (const float*)d_in[27] };

    const int B = in_sizes[0] / (2048 * Jn * 3);   // 128

    unsigned short* wbf = (unsigned short*)d_ws;                  // 3*33792 bf16 swizzled
    float* pb = (float*)(wbf + (size_t)3 * WSWZ);                 // 3*[96] f32 permuted bias
    unsigned short* X1 = (unsigned short*)(pb + 3 * NPAD);        // (B,1024,88) bf16
    unsigned short* X2 = X1 + (size_t)B * 1024 * C4;              // (B, 512,88) bf16

    {
        const int tot = 3 * WSWZ + 3 * NPAD;
        prep_weights<<<(tot + 255) / 256, 256, 0, stream>>>(c1w, c2w, c3w, c1b, c2b, c3b, wbf, pb);
    }

    conv_fused<2048, 0, 0><<<B * 16, 256, 0, stream>>>(input, offset, nullptr,
                                                       wbf, pb, X1, g1);
    conv_fused<1024, 1, 0><<<B * 8, 256, 0, stream>>>(nullptr, nullptr, X1,
                                                      wbf + WSWZ, pb + NPAD, X2, g2);
    conv_fused<512, 1, 1><<<B * 4, 256, 0, stream>>>(nullptr, nullptr, X2,
                                                     wbf + 2 * WSWZ, pb + 2 * NPAD, d_out, g2);
}